// Round 5
// baseline (452.302 us; speedup 1.0000x reference)
//
#include <hip/hip_runtime.h>
#include <math.h>

// Problem constants: B=128, FEW=64, D=512, E=16, O=512, H=64, K=3
constexpr int Dd  = 512;
constexpr int En  = 16;
constexpr int On  = 512;
constexpr int Hn  = 64;

// Workspace layout (bytes):
//   topi : int  [8192*4]   @ 0        -- top-3 expert ids (slot 3 unused)
//   topv : float[8192*4]   @ 131072   -- top-3 gate probs
//   A    : float[128*16*64]@ 262144   -- gate-weighted hidden accum
//   gsum : float[128*16]   @ 786432   -- gate mass per (batch, expert)

// ---------------------------------------------------------------------------
// K1: gating. 128 blocks x 256 threads; block = 64 tokens.
// Register-tiled 4 tok x 4 h per thread; x and gW1 both read straight from
// global (per-lane divergent addresses -> VMEM, L1/L2-cached, dedup'd).
// NO LDS in the inner loop (the LDS pipe is 1-per-CU and was the r4 limit).
// ---------------------------------------------------------------------------
__global__ __launch_bounds__(256) void k_gate(
    const float* __restrict__ x, const float* __restrict__ gW1,
    const float* __restrict__ gb1, const float* __restrict__ gW2,
    const float* __restrict__ gb2, int* __restrict__ topi,
    float* __restrict__ topv)
{
    __shared__ float g1l[64 * 68];    // hidden [tok][h], pad 68
    __shared__ float logl[64 * 17];   // logits (padded)
    __shared__ float w2l[64 * 16];
    __shared__ float b2l[16];

    const int tid = threadIdx.x;
    const int st  = tid & 15;         // token group (4 tokens)
    const int th  = tid >> 4;         // h group (4 h)
    const int t0  = blockIdx.x * 64;
    const int tb  = t0 + st * 4;

    #pragma unroll
    for (int k = 0; k < 4; k++) w2l[tid + k * 256] = gW2[tid + k * 256];
    if (tid < 16) b2l[tid] = gb2[tid];

    float acc[4][4];
    #pragma unroll
    for (int c = 0; c < 4; c++) {
        const float bv = gb1[th * 4 + c];
        #pragma unroll
        for (int i = 0; i < 4; i++) acc[i][c] = bv;
    }

    const float* xb[4];
    #pragma unroll
    for (int i = 0; i < 4; i++) xb[i] = x + (size_t)(tb + i) * Dd;
    const float* wb = gW1 + th * 4;   // gW1[d][64]

    // double-buffered 8-d groups
    float4 xcA[4], xcB[4], wc[8];
    #pragma unroll
    for (int j = 0; j < 8; j++) wc[j] = *(const float4*)(wb + j * 64);
    #pragma unroll
    for (int i = 0; i < 4; i++) {
        xcA[i] = *(const float4*)(xb[i]);
        xcB[i] = *(const float4*)(xb[i] + 4);
    }

    for (int d = 0; d < 512; d += 8) {
        const int dn = (d + 8) & 511;
        float4 xnA[4], xnB[4], wn[8];
        #pragma unroll
        for (int j = 0; j < 8; j++) wn[j] = *(const float4*)(wb + (dn + j) * 64);
        #pragma unroll
        for (int i = 0; i < 4; i++) {
            xnA[i] = *(const float4*)(xb[i] + dn);
            xnB[i] = *(const float4*)(xb[i] + dn + 4);
        }
        #pragma unroll
        for (int j = 0; j < 4; j++)
            #pragma unroll
            for (int i = 0; i < 4; i++) {
                const float xv = ((const float*)&xcA[i])[j];
                #pragma unroll
                for (int c = 0; c < 4; c++)
                    acc[i][c] = fmaf(xv, ((const float*)&wc[j])[c], acc[i][c]);
            }
        #pragma unroll
        for (int j = 0; j < 4; j++)
            #pragma unroll
            for (int i = 0; i < 4; i++) {
                const float xv = ((const float*)&xcB[i])[j];
                #pragma unroll
                for (int c = 0; c < 4; c++)
                    acc[i][c] = fmaf(xv, ((const float*)&wc[j + 4])[c], acc[i][c]);
            }
        #pragma unroll
        for (int j = 0; j < 8; j++) wc[j] = wn[j];
        #pragma unroll
        for (int i = 0; i < 4; i++) { xcA[i] = xnA[i]; xcB[i] = xnB[i]; }
    }

    // relu -> LDS (float4 store per token)
    #pragma unroll
    for (int i = 0; i < 4; i++) {
        float4 hv;
        hv.x = fmaxf(acc[i][0], 0.f);
        hv.y = fmaxf(acc[i][1], 0.f);
        hv.z = fmaxf(acc[i][2], 0.f);
        hv.w = fmaxf(acc[i][3], 0.f);
        *(float4*)&g1l[(st * 4 + i) * 68 + th * 4] = hv;
    }
    __syncthreads();

    // logits: 64 tokens x 16 experts = 1024 -> 4 per thread
    #pragma unroll
    for (int q = 0; q < 4; q++) {
        const int lid = tid + q * 256;
        const int tok = lid >> 4;
        const int e   = lid & 15;
        float sacc = b2l[e];
        const float* g = &g1l[tok * 68];
        #pragma unroll 8
        for (int h = 0; h < 64; h++) sacc = fmaf(g[h], w2l[h * 16 + e], sacc);
        logl[tok * 17 + e] = sacc;
    }
    __syncthreads();

    // softmax + top-3 (strict > keeps lowest index on ties, matching lax.top_k)
    if (tid < 64) {
        float v[16];
        float mx = -1e30f;
        #pragma unroll
        for (int e = 0; e < 16; e++) { v[e] = logl[tid * 17 + e]; mx = fmaxf(mx, v[e]); }
        float ssum = 0.f;
        #pragma unroll
        for (int e = 0; e < 16; e++) { v[e] = __expf(v[e] - mx); ssum += v[e]; }
        const float inv = 1.f / ssum;
        #pragma unroll
        for (int e = 0; e < 16; e++) v[e] *= inv;
        const int t = t0 + tid;
        unsigned mask = 0;
        for (int j = 0; j < 3; j++) {
            float bv = -1.f; int bi = 0;
            for (int e = 0; e < 16; e++) {
                if (!(mask & (1u << e)) && v[e] > bv) { bv = v[e]; bi = e; }
            }
            mask |= (1u << bi);
            topi[t * 4 + j] = bi;
            topv[t * 4 + j] = bv;
        }
    }
}

// ---------------------------------------------------------------------------
// K2: sparse expert fc1 + gate-weighted accumulation.
// Grid 512 = 16 experts x 32 slices of 256 tokens. Block (e,s) owns
// A[4s..4s+3, e, :] -> plain stores. Register-tiled 4 slots x 4 h per
// thread; x (gathered) and W1[e] read straight from global per-lane.
// LDS only for compaction lists and the Ap reduction. Double-buffered
// 4-d groups; zero DS instructions in the d-loop.
// ---------------------------------------------------------------------------
__global__ __launch_bounds__(256) void k_expert(
    const float* __restrict__ x, const float* __restrict__ W1,
    const float* __restrict__ b1, const int* __restrict__ topi,
    const float* __restrict__ topv, float* __restrict__ A,
    float* __restrict__ gsum)
{
    __shared__ int   lt[256];
    __shared__ float lv[256];
    __shared__ float Ap[4 * 64];
    __shared__ float gp[4];
    __shared__ int   cnt;

    const int tid = threadIdx.x;
    const int st  = tid & 15;          // slot group (4 slots)
    const int th  = tid >> 4;          // h group (4 h)
    const int e   = blockIdx.x >> 5;   // expert 0..15
    const int s   = blockIdx.x & 31;   // slice 0..31
    const int ts  = s * 256;

    if (tid == 0) cnt = 0;
    Ap[tid] = 0.f;
    if (tid < 4) gp[tid] = 0.f;
    __syncthreads();

    // compaction: 1 token per thread
    {
        const int t = ts + tid;
        const int4   ti = *(const int4*)(topi + t * 4);
        const float4 tv = *(const float4*)(topv + t * 4);
        const int   idx[3] = { ti.x, ti.y, ti.z };
        const float val[3] = { tv.x, tv.y, tv.z };
        #pragma unroll
        for (int j = 0; j < 3; j++) {
            if (idx[j] == e) {
                const int p = atomicAdd(&cnt, 1);
                lt[p] = tid;
                lv[p] = val[j];
                atomicAdd(&gp[tid >> 6], val[j]);
            }
        }
    }
    __syncthreads();
    const int n = cnt;   // block-uniform

    float b1f[4];
    #pragma unroll
    for (int c = 0; c < 4; c++) b1f[c] = b1[e * 64 + th * 4 + c];
    const float* __restrict__ W1e = W1 + (size_t)e * (Dd * Hn);
    const float* wb = W1e + th * 4;

    for (int bs = 0; bs < n; bs += 64) {    // uniform trip count
        float gv[4]; int bl[4]; const float* xb[4];
        #pragma unroll
        for (int i = 0; i < 4; i++) {
            const int sl = bs + st * 4 + i;
            const int tt = (sl < n) ? lt[sl] : 0;
            gv[i] = (sl < n) ? lv[sl] : 0.f;
            bl[i] = tt >> 6;
            xb[i] = x + (size_t)(ts + tt) * Dd;
        }
        float acc[4][4];
        #pragma unroll
        for (int i = 0; i < 4; i++)
            #pragma unroll
            for (int c = 0; c < 4; c++) acc[i][c] = 0.f;

        // double-buffered 4-d groups
        float4 xc[4], wc[4];
        #pragma unroll
        for (int j = 0; j < 4; j++) wc[j] = *(const float4*)(wb + j * 64);
        #pragma unroll
        for (int i = 0; i < 4; i++) xc[i] = *(const float4*)(xb[i]);

        for (int d = 0; d < 512; d += 4) {
            const int dn = (d + 4) & 511;
            float4 xn[4], wn[4];
            #pragma unroll
            for (int j = 0; j < 4; j++) wn[j] = *(const float4*)(wb + (dn + j) * 64);
            #pragma unroll
            for (int i = 0; i < 4; i++) xn[i] = *(const float4*)(xb[i] + dn);
            #pragma unroll
            for (int j = 0; j < 4; j++)
                #pragma unroll
                for (int i = 0; i < 4; i++) {
                    const float xv = ((const float*)&xc[i])[j];
                    #pragma unroll
                    for (int c = 0; c < 4; c++)
                        acc[i][c] = fmaf(xv, ((const float*)&wc[j])[c], acc[i][c]);
                }
            #pragma unroll
            for (int j = 0; j < 4; j++) wc[j] = wn[j];
            #pragma unroll
            for (int i = 0; i < 4; i++) xc[i] = xn[i];
        }

        // relu + gate-weight + LDS accumulate
        #pragma unroll
        for (int i = 0; i < 4; i++)
            #pragma unroll
            for (int c = 0; c < 4; c++) {
                const float h = fmaxf(acc[i][c] + b1f[c], 0.f);
                atomicAdd(&Ap[bl[i] * 64 + th * 4 + c], gv[i] * h);
            }
    }
    __syncthreads();

    // sole owner of (4s..4s+3, e) -> plain stores (also covers ws poison)
    {
        const int bl2 = tid >> 6, h = tid & 63;
        A[(size_t)(s * 4 + bl2) * (En * Hn) + e * 64 + h] = Ap[tid];
    }
    if (tid < 4) gsum[(s * 4 + tid) * En + e] = gp[tid];
}

// ---------------------------------------------------------------------------
// K3: out[b, o] = (A[b] . W2 + gsum[b] . b2) / 64
// Grid 256 = 32 batch-quads x 8 column-octs. Wave = one batch; lane = one
// output column. W2 rows coalesced 256 B; A read as wave-broadcast global
// loads (L2-resident, dedup'd) -- no LDS at all.
// ---------------------------------------------------------------------------
__global__ __launch_bounds__(256) void k_out(
    const float* __restrict__ W2, const float* __restrict__ b2,
    const float* __restrict__ A, const float* __restrict__ gsum,
    float* __restrict__ out)
{
    const int tid = threadIdx.x;
    const int ln  = tid & 63;
    const int wv  = tid >> 6;              // wave = which of 4 batches
    const int bq  = blockIdx.x >> 3;       // 0..31
    const int oc  = blockIdx.x & 7;        // 0..7
    const int b   = bq * 4 + wv;
    const int o   = oc * 64 + ln;

    const float* Ab  = A + (size_t)b * 1024;
    const float* w2p = W2 + o;
    float a = 0.f;

    float wcv[8];
    float4 a0 = *(const float4*)(Ab);
    float4 a1 = *(const float4*)(Ab + 4);
    #pragma unroll
    for (int j = 0; j < 8; j++) wcv[j] = w2p[(size_t)j * On];

    for (int eh = 0; eh < 1024; eh += 8) {
        const int en = (eh + 8) & 1023;
        float wn[8];
        float4 a0n = *(const float4*)(Ab + en);
        float4 a1n = *(const float4*)(Ab + en + 4);
        #pragma unroll
        for (int j = 0; j < 8; j++) wn[j] = w2p[(size_t)(en + j) * On];
        a = fmaf(a0.x, wcv[0], a);
        a = fmaf(a0.y, wcv[1], a);
        a = fmaf(a0.z, wcv[2], a);
        a = fmaf(a0.w, wcv[3], a);
        a = fmaf(a1.x, wcv[4], a);
        a = fmaf(a1.y, wcv[5], a);
        a = fmaf(a1.z, wcv[6], a);
        a = fmaf(a1.w, wcv[7], a);
        #pragma unroll
        for (int j = 0; j < 8; j++) wcv[j] = wn[j];
        a0 = a0n; a1 = a1n;
    }
    const float* gb = gsum + (size_t)b * En;
    #pragma unroll
    for (int ee = 0; ee < 16; ee++) a = fmaf(gb[ee], b2[ee * On + o], a);

    out[(size_t)b * On + o] = a * (1.f / 64.f);
}

// ---------------------------------------------------------------------------
extern "C" void kernel_launch(void* const* d_in, const int* in_sizes, int n_in,
                              void* d_out, int out_size, void* d_ws, size_t ws_size,
                              hipStream_t stream)
{
    (void)in_sizes; (void)n_in; (void)out_size; (void)ws_size;
    const float* x   = (const float*)d_in[0];
    const float* gW1 = (const float*)d_in[1];
    const float* gb1 = (const float*)d_in[2];
    const float* gW2 = (const float*)d_in[3];
    const float* gb2 = (const float*)d_in[4];
    const float* W1  = (const float*)d_in[5];
    const float* b1  = (const float*)d_in[6];
    const float* W2  = (const float*)d_in[7];
    const float* b2  = (const float*)d_in[8];
    float* out = (float*)d_out;

    char* ws = (char*)d_ws;
    int*   topi = (int*)(ws);
    float* topv = (float*)(ws + 131072);
    float* A    = (float*)(ws + 262144);
    float* gsum = (float*)(ws + 786432);

    k_gate  <<<dim3(128), dim3(256), 0, stream>>>(x, gW1, gb1, gW2, gb2, topi, topv);
    k_expert<<<dim3(512), dim3(256), 0, stream>>>(x, W1, b1, topi, topv, A, gsum);
    k_out   <<<dim3(256), dim3(256), 0, stream>>>(W2, b2, A, gsum, out);
}

// Round 9
// 421.231 us; speedup vs baseline: 1.0738x; 1.0738x over previous
//
#include <hip/hip_runtime.h>
#include <math.h>

// Problem constants: B=128, FEW=64, D=512, E=16, O=512, H=64, K=3
constexpr int Dd = 512;
constexpr int En = 16;
constexpr int On = 512;
constexpr int Hn = 64;
constexpr int CAP = 4096;          // per-expert token-list capacity (avg 1536)

// Workspace layout (bytes):
//   A    : float[128*16*64] @ 0        (524288)  -- gate-weighted hidden accum
//   gsum : float[128*16]    @ 524288   (  8192)  -- gate mass per (batch, expert)
//   cnt  : int[16]          @ 532480   (    64)  -- per-expert list counts
//   lt   : int[16*CAP]      @ 532544   (262144)  -- per-expert token lists
//   lv   : float[16*CAP]    @ 794688   (262144)  -- per-expert gate values
// A/gsum/cnt zeroed by k_zero each launch (ws is poisoned 0xAA).

// ---------------------------------------------------------------------------
// K0: zero A + gsum + cnt (533504/4 = 133376 words; covers first 533504 B).
// Graph-capture-safe by construction (plain kernel, no runtime API).
// ---------------------------------------------------------------------------
__global__ __launch_bounds__(256) void k_zero(int* __restrict__ p)
{
    const int i = blockIdx.x * 256 + threadIdx.x;
    if (i < 133136) p[i] = 0;   // 532544 bytes = A + gsum + cnt
}

// ---------------------------------------------------------------------------
// K1: gating + compaction. 128 blocks x 512 threads; block = 64 tokens.
// lane = token, wave = h-eighth (8 h per wave). x: per-lane VMEM float4
// (vmcnt-pipelined). gW1: wave-uniform address (readfirstlane'd h0) ->
// s_load; FMAs use SGPR weight operands. No LDS in the d-loop.
// Then logits/softmax/top-3 per token, appending to per-expert lists.
// ---------------------------------------------------------------------------
__global__ __launch_bounds__(512) void k_gate(
    const float* __restrict__ x, const float* __restrict__ gW1,
    const float* __restrict__ gb1, const float* __restrict__ gW2,
    const float* __restrict__ gb2,
    int* __restrict__ cnt, int* __restrict__ lt, float* __restrict__ lv)
{
    __shared__ float g1l[64 * 68];    // hidden [tok][h], padded
    __shared__ float logl[64 * 17];   // logits [tok][e], padded
    __shared__ float w2l[64 * 16];
    __shared__ float b2l[16];

    const int tid = threadIdx.x;
    const int ln  = tid & 63;                               // token in block
    const int w8  = tid >> 6;                               // h-eighth 0..7
    const int h0  = __builtin_amdgcn_readfirstlane(w8 * 8); // uniform -> SGPR
    const int t0  = blockIdx.x * 64;
    const float* __restrict__ xr = x + (size_t)(t0 + ln) * Dd;

    #pragma unroll
    for (int k = 0; k < 2; k++) w2l[tid + k * 512] = gW2[tid + k * 512];
    if (tid < 16) b2l[tid] = gb2[tid];

    float acc[8];
    #pragma unroll
    for (int c = 0; c < 8; c++) acc[c] = gb1[h0 + c];   // uniform s_load

    // d-loop: per-lane x float4 pairs (VMEM, prefetched), w via s_load
    float4 xv0 = *(const float4*)(xr);
    float4 xv1 = *(const float4*)(xr + 4);
    for (int d = 0; d < 512; d += 8) {
        const int dn = (d + 8) & 511;        // branch-free tail prefetch
        float4 xn0 = *(const float4*)(xr + dn);
        float4 xn1 = *(const float4*)(xr + dn + 4);
        const float* wd = gW1 + (size_t)d * 64 + h0;   // uniform base
        #pragma unroll
        for (int j = 0; j < 4; j++) {
            const float xs = ((const float*)&xv0)[j];
            #pragma unroll
            for (int c = 0; c < 8; c++)
                acc[c] = fmaf(xs, wd[j * 64 + c], acc[c]);
        }
        #pragma unroll
        for (int j = 0; j < 4; j++) {
            const float xs = ((const float*)&xv1)[j];
            #pragma unroll
            for (int c = 0; c < 8; c++)
                acc[c] = fmaf(xs, wd[(j + 4) * 64 + c], acc[c]);
        }
        xv0 = xn0; xv1 = xn1;
    }

    // relu -> LDS ([tok][68] padded; 16B-aligned stores)
    {
        float4 hv0, hv1;
        hv0.x = fmaxf(acc[0], 0.f); hv0.y = fmaxf(acc[1], 0.f);
        hv0.z = fmaxf(acc[2], 0.f); hv0.w = fmaxf(acc[3], 0.f);
        hv1.x = fmaxf(acc[4], 0.f); hv1.y = fmaxf(acc[5], 0.f);
        hv1.z = fmaxf(acc[6], 0.f); hv1.w = fmaxf(acc[7], 0.f);
        *(float4*)&g1l[ln * 68 + h0]     = hv0;
        *(float4*)&g1l[ln * 68 + h0 + 4] = hv1;
    }
    __syncthreads();

    // logits: 64 tok x 16 e = 1024 -> 2 per thread
    #pragma unroll
    for (int q = 0; q < 2; q++) {
        const int lid = tid * 2 + q;
        const int tok = lid >> 4;
        const int e   = lid & 15;
        float s = b2l[e];
        const float* g = &g1l[tok * 68];
        #pragma unroll 8
        for (int h = 0; h < 64; h++) s = fmaf(g[h], w2l[h * 16 + e], s);
        logl[tok * 17 + e] = s;
    }
    __syncthreads();

    // softmax + top-3 (strict > keeps lowest index on ties, matching
    // lax.top_k) + append to per-expert global lists
    if (tid < 64) {
        float v[16];
        float mx = -1e30f;
        #pragma unroll
        for (int e = 0; e < 16; e++) { v[e] = logl[tid * 17 + e]; mx = fmaxf(mx, v[e]); }
        float ssum = 0.f;
        #pragma unroll
        for (int e = 0; e < 16; e++) { v[e] = __expf(v[e] - mx); ssum += v[e]; }
        const float inv = 1.f / ssum;
        #pragma unroll
        for (int e = 0; e < 16; e++) v[e] *= inv;
        const int t = t0 + tid;
        unsigned mask = 0;
        for (int j = 0; j < 3; j++) {
            float bv = -1.f; int bi = 0;
            for (int e = 0; e < 16; e++) {
                if (!(mask & (1u << e)) && v[e] > bv) { bv = v[e]; bi = e; }
            }
            mask |= (1u << bi);
            const int p = atomicAdd(&cnt[bi], 1);
            if (p < CAP) { lt[bi * CAP + p] = t; lv[bi * CAP + p] = bv; }
        }
    }
}

// ---------------------------------------------------------------------------
// K2: sparse expert fc1 + gate-weighted accumulation into A (atomic).
// Grid (24, 4, 16) = slot-blocks x h-quarters x experts; block = ONE wave.
// lane = compacted token slot. All weight/bias addresses are blockIdx-
// derived -> SGPR-uniform -> s_load; FMAs are v_fma(vacc, s_w, v_x).
// x per-lane VMEM float4, double-buffered. No LDS, no barriers.
// d-groups of 4 (64 weight floats per scalar batch, fits SGPR budget).
// ---------------------------------------------------------------------------
__global__ __launch_bounds__(64) void k_expert(
    const float* __restrict__ x, const float* __restrict__ W1,
    const float* __restrict__ b1, const int* __restrict__ cnt,
    const int* __restrict__ lt, const float* __restrict__ lv,
    float* __restrict__ A, float* __restrict__ gsum)
{
    const int ln = threadIdx.x;
    const int e  = blockIdx.z;
    const int h0 = blockIdx.y * 16;
    int n = cnt[e];                              // uniform s_load
    n = (n < CAP) ? n : CAP;                     // capacity clamp

    const float* __restrict__ W1e = W1 + (size_t)e * (Dd * Hn) + h0;
    float b1f[16];
    #pragma unroll
    for (int c = 0; c < 16; c++) b1f[c] = b1[e * 64 + h0 + c];
    const int*   lte = lt + e * CAP;
    const float* lve = lv + e * CAP;

    for (int base = blockIdx.x * 64; base < n; base += 24 * 64) {
        const int  sl = base + ln;
        const bool ok = sl < n;
        const int   t = ok ? lte[sl] : 0;
        const float v = ok ? lve[sl] : 0.f;      // v=0 -> contributes nothing
        const float* __restrict__ xr = x + (size_t)t * Dd;

        float acc[16];
        #pragma unroll
        for (int c = 0; c < 16; c++) acc[c] = 0.f;

        float4 xv = *(const float4*)(xr);
        for (int d = 0; d < 512; d += 4) {
            const int dn = (d + 4) & 511;        // branch-free tail prefetch
            float4 xn = *(const float4*)(xr + dn);
            const float* wd = W1e + (size_t)d * 64;   // uniform base
            #pragma unroll
            for (int j = 0; j < 4; j++) {
                const float xs = ((const float*)&xv)[j];
                #pragma unroll
                for (int c = 0; c < 16; c++)
                    acc[c] = fmaf(xs, wd[j * 64 + c], acc[c]);
            }
            xv = xn;
        }

        const int b = t >> 6;                    // batch of this token
        float* Ab = A + (size_t)b * (En * Hn) + e * 64 + h0;
        #pragma unroll
        for (int c = 0; c < 16; c++) {
            const float h = fmaxf(acc[c] + b1f[c], 0.f);
            atomicAdd(&Ab[c], v * h);
        }
        if (blockIdx.y == 0) atomicAdd(&gsum[b * En + e], v);
    }
}

// ---------------------------------------------------------------------------
// K3: out[b, o] = (A[b] . W2 + gsum[b] . b2) / 64
// Grid 256 = 32 batch-quads x 8 column-octs. Wave = one batch; lane = one
// output column. W2 rows coalesced 256 B; A wave-broadcast global loads.
// ---------------------------------------------------------------------------
__global__ __launch_bounds__(256) void k_out(
    const float* __restrict__ W2, const float* __restrict__ b2,
    const float* __restrict__ A, const float* __restrict__ gsum,
    float* __restrict__ out)
{
    const int tid = threadIdx.x;
    const int ln  = tid & 63;
    const int wv  = tid >> 6;
    const int bq  = blockIdx.x >> 3;
    const int oc  = blockIdx.x & 7;
    const int b   = bq * 4 + wv;
    const int o   = oc * 64 + ln;

    const float* Ab  = A + (size_t)b * 1024;
    const float* w2p = W2 + o;
    float a = 0.f;

    float wcv[8];
    float4 a0 = *(const float4*)(Ab);
    float4 a1 = *(const float4*)(Ab + 4);
    #pragma unroll
    for (int j = 0; j < 8; j++) wcv[j] = w2p[(size_t)j * On];

    for (int eh = 0; eh < 1024; eh += 8) {
        const int en = (eh + 8) & 1023;
        float wn[8];
        float4 a0n = *(const float4*)(Ab + en);
        float4 a1n = *(const float4*)(Ab + en + 4);
        #pragma unroll
        for (int j = 0; j < 8; j++) wn[j] = w2p[(size_t)(en + j) * On];
        a = fmaf(a0.x, wcv[0], a);
        a = fmaf(a0.y, wcv[1], a);
        a = fmaf(a0.z, wcv[2], a);
        a = fmaf(a0.w, wcv[3], a);
        a = fmaf(a1.x, wcv[4], a);
        a = fmaf(a1.y, wcv[5], a);
        a = fmaf(a1.z, wcv[6], a);
        a = fmaf(a1.w, wcv[7], a);
        #pragma unroll
        for (int j = 0; j < 8; j++) wcv[j] = wn[j];
        a0 = a0n; a1 = a1n;
    }
    const float* gb = gsum + (size_t)b * En;
    #pragma unroll
    for (int ee = 0; ee < 16; ee++) a = fmaf(gb[ee], b2[ee * On + o], a);

    out[(size_t)b * On + o] = a * (1.f / 64.f);
}

// ---------------------------------------------------------------------------
extern "C" void kernel_launch(void* const* d_in, const int* in_sizes, int n_in,
                              void* d_out, int out_size, void* d_ws, size_t ws_size,
                              hipStream_t stream)
{
    (void)in_sizes; (void)n_in; (void)out_size; (void)ws_size;
    const float* x   = (const float*)d_in[0];
    const float* gW1 = (const float*)d_in[1];
    const float* gb1 = (const float*)d_in[2];
    const float* gW2 = (const float*)d_in[3];
    const float* gb2 = (const float*)d_in[4];
    const float* W1  = (const float*)d_in[5];
    const float* b1  = (const float*)d_in[6];
    const float* W2  = (const float*)d_in[7];
    const float* b2  = (const float*)d_in[8];
    float* out = (float*)d_out;

    char* ws = (char*)d_ws;
    float* A    = (float*)(ws);
    float* gsum = (float*)(ws + 524288);
    int*   cnt  = (int*)(ws + 532480);
    int*   lt   = (int*)(ws + 532544);
    float* lv   = (float*)(ws + 794688);

    // zero A + gsum + cnt (ws is poisoned 0xAA before every timed launch)
    k_zero  <<<dim3(521), dim3(256), 0, stream>>>((int*)ws);

    k_gate  <<<dim3(128), dim3(512), 0, stream>>>(x, gW1, gb1, gW2, gb2,
                                                  cnt, lt, lv);
    k_expert<<<dim3(24, 4, 16), dim3(64), 0, stream>>>(x, W1, b1, cnt, lt, lv,
                                                       A, gsum);
    k_out   <<<dim3(256), dim3(256), 0, stream>>>(W2, b2, A, gsum, out);
}